// Round 1
// baseline (1424.415 us; speedup 1.0000x reference)
//
#include <hip/hip_runtime.h>

// Sizes (fixed by the problem)
#define NB  128
#define ND  1024
#define NH1 512
#define NH2 128

__device__ __forceinline__ float sigm(float v) { return 1.0f / (1.0f + __expf(-v)); }

// out[r,c] = (SIG? sigmoid : id)(dot(X[r,:K], W[c,:K]) + bias[c])
// X [R,K] row-major, W [COLS,K] row-major. One thread per output.
template<int K, int COLS, bool SIG>
__global__ __launch_bounds__(256)
void fc_kernel(const float* __restrict__ X, const float* __restrict__ W,
               const float* __restrict__ bias, float* __restrict__ Cout,
               float* __restrict__ Sout) {
    int idx = blockIdx.x * 256 + threadIdx.x;
    int r = idx / COLS, c = idx % COLS;
    const float4* xr = (const float4*)(X + (long)r * K);
    const float4* wr = (const float4*)(W + (long)c * K);
    float acc = 0.f;
#pragma unroll 4
    for (int k = 0; k < K / 4; k++) {
        float4 a = xr[k], b = wr[k];
        acc += a.x * b.x + a.y * b.y + a.z * b.z + a.w * b.w;
    }
    acc += bias[c];
    if (SIG) {
        float cv = sigm(acc);
        Cout[idx] = cv;
        Sout[idx] = cv * (1.f - cv);
    } else {
        Cout[idx] = acc;
    }
}

// Batched GEMM: C[b] = (A[b] * kscale[b][k]) @ Bm[b], optionally col-scaled by nscale[b][n].
// A [M,K] row-major (batch stride aBs; 0 = shared), Bm [K,N] row-major (stride bBs),
// C [M,N] row-major (stride cBs). 64x64 tile, BK=16, 256 threads, 4x4 per thread.
template<int K, bool KSCALE, bool NSCALE>
__global__ __launch_bounds__(256)
void bgemm_kernel(const float* __restrict__ A, long aBs,
                  const float* __restrict__ Bm, long bBs,
                  const float* __restrict__ ks,   // [NB,K] or null
                  const float* __restrict__ ns,   // [NB,N] or null
                  float* __restrict__ Cmat, long cBs,
                  int M, int N) {
    int b = blockIdx.z;
    const float* Ab = A + (long)b * aBs;
    const float* Bb = Bm + (long)b * bBs;
    float* Cb = Cmat + (long)b * cBs;
    int m0 = blockIdx.y * 64, n0 = blockIdx.x * 64;

    __shared__ float As[16][64];   // k-major (transposed) A tile
    __shared__ float Bs[16][64];

    int t = threadIdx.x;
    int tx = t & 15, ty = t >> 4;       // output 4x4 at (ty*4, tx*4)
    int lm  = t & 63;                    // A-load row within tile
    int lkq = t >> 6;                    // A-load k-quad (0..3)
    int lbk = t >> 4;                    // B-load k row (0..15)
    int lbn = (t & 15) * 4;              // B-load col quad

    float acc[4][4] = {{0.f}};

    for (int k0 = 0; k0 < K; k0 += 16) {
        float4 av = *(const float4*)(Ab + (long)(m0 + lm) * K + k0 + lkq * 4);
        if (KSCALE) {
            float4 sv = *(const float4*)(ks + (long)b * K + k0 + lkq * 4);
            av.x *= sv.x; av.y *= sv.y; av.z *= sv.z; av.w *= sv.w;
        }
        float4 bv = *(const float4*)(Bb + (long)(k0 + lbk) * N + n0 + lbn);
        __syncthreads();   // previous tile's compute done before overwrite
        As[lkq * 4 + 0][lm] = av.x;
        As[lkq * 4 + 1][lm] = av.y;
        As[lkq * 4 + 2][lm] = av.z;
        As[lkq * 4 + 3][lm] = av.w;
        *(float4*)(&Bs[lbk][lbn]) = bv;
        __syncthreads();
#pragma unroll
        for (int kk = 0; kk < 16; kk++) {
            float4 a  = *(const float4*)(&As[kk][ty * 4]);
            float4 bq = *(const float4*)(&Bs[kk][tx * 4]);
            acc[0][0] += a.x * bq.x; acc[0][1] += a.x * bq.y; acc[0][2] += a.x * bq.z; acc[0][3] += a.x * bq.w;
            acc[1][0] += a.y * bq.x; acc[1][1] += a.y * bq.y; acc[1][2] += a.y * bq.z; acc[1][3] += a.y * bq.w;
            acc[2][0] += a.z * bq.x; acc[2][1] += a.z * bq.y; acc[2][2] += a.z * bq.z; acc[2][3] += a.z * bq.w;
            acc[3][0] += a.w * bq.x; acc[3][1] += a.w * bq.y; acc[3][2] += a.w * bq.z; acc[3][3] += a.w * bq.w;
        }
    }

    float4 sv = {1.f, 1.f, 1.f, 1.f};
    if (NSCALE) sv = *(const float4*)(ns + (long)b * N + n0 + tx * 4);
#pragma unroll
    for (int i = 0; i < 4; i++) {
        float4 r;
        r.x = acc[i][0] * sv.x;
        r.y = acc[i][1] * sv.y;
        r.z = acc[i][2] * sv.z;
        r.w = acc[i][3] * sv.w;
        *(float4*)(Cb + (long)(m0 + ty * 4 + i) * N + n0 + tx * 4) = r;
    }
}

extern "C" void kernel_launch(void* const* d_in, const int* in_sizes, int n_in,
                              void* d_out, int out_size, void* d_ws, size_t ws_size,
                              hipStream_t stream) {
    const float* x  = (const float*)d_in[0];
    const float* W1 = (const float*)d_in[1];
    const float* b1 = (const float*)d_in[2];
    const float* W2 = (const float*)d_in[3];
    const float* b2 = (const float*)d_in[4];
    const float* W3 = (const float*)d_in[5];
    const float* b3 = (const float*)d_in[6];
    const float* W4 = (const float*)d_in[7];
    const float* b4 = (const float*)d_in[8];

    // Output layout: recover [128*1024] | c2 [128*128] | Jac [128*1024*1024]
    float* out_rec = (float*)d_out;
    float* out_c2  = out_rec + NB * ND;
    float* out_jac = out_c2 + NB * NH2;

    // Workspace layout (floats): c1, s1, s2, c3, s3, R [B,128,1024], L [B,1024,128]
    float* ws = (float*)d_ws;
    float* c1 = ws;                       // 65536
    float* s1 = c1 + NB * NH1;            // 65536
    float* s2 = s1 + NB * NH1;            // 16384
    float* c3 = s2 + NB * NH2;            // 65536
    float* s3 = c3 + NB * NH1;            // 65536
    float* Rb = s3 + NB * NH1;            // 128*128*1024 = 16777216
    float* Lb = Rb + (long)NB * NH2 * ND; // 128*1024*128 = 16777216

    // Forward pass (stores c & s = c*(1-c))
    fc_kernel<ND,  NH1, true ><<<NB * NH1 / 256, 256, 0, stream>>>(x,       W1, b1, c1,      s1);
    fc_kernel<NH1, NH2, true ><<<NB * NH2 / 256, 256, 0, stream>>>(c1,      W2, b2, out_c2,  s2);
    fc_kernel<NH2, NH1, true ><<<NB * NH1 / 256, 256, 0, stream>>>(out_c2,  W3, b3, c3,      s3);
    fc_kernel<NH1, ND,  false><<<NB * ND  / 256, 256, 0, stream>>>(c3,      W4, b4, out_rec, nullptr);

    // R[b] = (W2 .* s1[b]) @ W1   : M=128, N=1024, K=512
    bgemm_kernel<NH1, true, false><<<dim3(ND / 64, NH2 / 64, NB), 256, 0, stream>>>(
        W2, 0, W1, 0, s1, nullptr, Rb, (long)NH2 * ND, NH2, ND);

    // L[b] = ((W4 .* s3[b]) @ W3) .* s2[b]  : M=1024, N=128, K=512
    bgemm_kernel<NH1, true, true><<<dim3(NH2 / 64, ND / 64, NB), 256, 0, stream>>>(
        W4, 0, W3, 0, s3, s2, Lb, (long)ND * NH2, ND, NH2);

    // Jac[b] = L[b] @ R[b]  : M=1024, N=1024, K=128
    bgemm_kernel<NH2, false, false><<<dim3(ND / 64, ND / 64, NB), 256, 0, stream>>>(
        Lb, (long)ND * NH2, Rb, (long)NH2 * ND, nullptr, nullptr,
        out_jac, (long)ND * ND, ND, ND);
}